// Round 5
// baseline (20564.392 us; speedup 1.0000x reference)
//
#include <hip/hip_runtime.h>

#define T_STEPS 8192
#define DD 1024
#define HH 1024
#define NWG 256
#define NTHR 512
#define SCOPE_AGENT __HIP_MEMORY_SCOPE_AGENT
typedef unsigned long long u64;

// XOR swizzle (float index) so the 4 segs of a wave hit distinct bank quads
// when broadcasting 16B chunks to 16 lanes each.
__device__ __forceinline__ int swz(int k) { return k ^ ((((k) >> 6) & 3) << 2); }

__device__ __forceinline__ float fsig(float v) {
  return 1.f / (1.f + __expf(-v));
}
__device__ __forceinline__ float ftanh(float v) {
  return 2.f / (1.f + __expf(-2.f * v)) - 1.f;
}

// Persistent scan: WG g owns h[4g..4g+4). Thread (seg=tid>>4, col=tid&15)
// covers rows k=seg*64..+64 of the 2048-long dot for z-column
// (gate=col>>2)*H + g*4 + (col&3). segs 0..15 = x-part, 16..31 = h-part.
// Weights: 64 floats/thread held in VGPRs (16 float4, static indices only,
// keep-alive asm so the compiler cannot sink the loads into the loop).
// h travels as 64-bit (tag<<32 | float_bits) atoms, ping-ponged over 2 slots;
// polls are issued LATE (phase C, after the x-dot) so the first poll
// almost always hits -> exactly one L3 round trip (round-4 lesson).
__global__ __launch_bounds__(NTHR, 2) void lstm_scan(
    const float* __restrict__ x, const float* __restrict__ c_in,
    const float* __restrict__ h_in, const float* __restrict__ W,
    const float* __restrict__ b, float* __restrict__ Hs,  // [T][H] = h_1..h_T
    u64* __restrict__ hbuf,         // [2][H] tagged ping-pong (memset 0)
    float* __restrict__ out_tail)   // c_last | h_last
{
  const int g = blockIdx.x, tid = threadIdx.x;
  const int lane = tid & 63, wave = tid >> 6;
  const int col = tid & 15, seg = tid >> 4;
  const int gate = col >> 2, hi = col & 3;
  const int cg = gate * HH + g * 4 + hi;

  __shared__ float xb[DD];          // swizzled x_t
  __shared__ float hb[HH];          // swizzled h_{t-1}
  __shared__ float partial[8][16];  // per-wave column partials

  float c_reg = 0.f, hlast = 0.f;

  // Publish h_0 immediately (slot 0, tag 1) so consumers' first polls hit.
  if (tid < 4) {
    const float h0 = h_in[g * 4 + tid];
    c_reg = c_in[g * 4 + tid];
    const u64 pv = ((u64)1u << 32) | (u64)__float_as_uint(h0);
    __hip_atomic_store(&hbuf[g * 4 + tid], pv, __ATOMIC_RELAXED, SCOPE_AGENT);
  }

  // Weights -> VGPRs (one-time). 16 float4 = 64 VGPRs.
  float4 wr[16];
  #pragma unroll
  for (int j = 0; j < 16; ++j) {
    wr[j].x = W[(size_t)(seg * 64 + j * 4 + 0) * (4 * HH) + cg];
    wr[j].y = W[(size_t)(seg * 64 + j * 4 + 1) * (4 * HH) + cg];
    wr[j].z = W[(size_t)(seg * 64 + j * 4 + 2) * (4 * HH) + cg];
    wr[j].w = W[(size_t)(seg * 64 + j * 4 + 3) * (4 * HH) + cg];
  }
  // Keep-alive: opaque def prevents rematerializing the loads in the loop.
  #pragma unroll
  for (int j = 0; j < 16; ++j)
    asm volatile("" : "+v"(wr[j].x), "+v"(wr[j].y), "+v"(wr[j].z), "+v"(wr[j].w));

  // Loop-invariant bias for this thread's column (used by wave 0 only).
  const float bias_reg = b[((lane & 15) >> 2) * HH + g * 4 + (lane & 3)];

  // Prefetch x_1 into registers.
  float xv0 = x[tid], xv1 = x[tid + 512];

  __syncthreads();

  const bool is_x = (seg < 16);
  const int s2 = seg - 16;

  for (int t = 1; t <= T_STEPS; ++t) {
    // A: stage x_t from prefetch regs (no global stall on the serial chain).
    xb[swz(tid)]       = xv0;
    xb[swz(tid + 512)] = xv1;
    __syncthreads();  // xb ready; prev-step partial reads done

    // B: prefetch x_{t+1} (latency hidden under x-dot + poll); x-half dot.
    if (t < T_STEPS) {
      const float* xn = x + (size_t)t * DD;
      xv0 = xn[tid];
      xv1 = xn[tid + 512];
    }
    if (is_x) {
      float p = 0.f;
      #pragma unroll
      for (int j = 0; j < 16; ++j) {
        const float4 xv = *(const float4*)&xb[(seg * 64 + j * 4) ^ ((seg & 3) << 2)];
        p = fmaf(xv.x, wr[j].x, p); p = fmaf(xv.y, wr[j].y, p);
        p = fmaf(xv.z, wr[j].z, p); p = fmaf(xv.w, wr[j].w, p);
      }
      p += __shfl_xor(p, 16);
      p += __shfl_xor(p, 32);
      if (lane < 16) partial[wave][lane] = p;
    }

    // C: poll tagged h atoms (fresh issue -> first poll usually hits).
    {
      const u64* hp = hbuf + ((t - 1) & 1) * HH;
      u64 v0 = __hip_atomic_load(&hp[tid],       __ATOMIC_RELAXED, SCOPE_AGENT);
      u64 v1 = __hip_atomic_load(&hp[tid + 512], __ATOMIC_RELAXED, SCOPE_AGENT);
      bool r0 = (unsigned)(v0 >> 32) >= (unsigned)t;
      bool r1 = (unsigned)(v1 >> 32) >= (unsigned)t;
      while (!(r0 && r1)) {
        __builtin_amdgcn_s_sleep(1);
        if (!r0) {
          v0 = __hip_atomic_load(&hp[tid], __ATOMIC_RELAXED, SCOPE_AGENT);
          r0 = (unsigned)(v0 >> 32) >= (unsigned)t;
        }
        if (!r1) {
          v1 = __hip_atomic_load(&hp[tid + 512], __ATOMIC_RELAXED, SCOPE_AGENT);
          r1 = (unsigned)(v1 >> 32) >= (unsigned)t;
        }
      }
      hb[swz(tid)]       = __uint_as_float((unsigned)v0);
      hb[swz(tid + 512)] = __uint_as_float((unsigned)v1);
    }
    __syncthreads();  // hb ready + x-partials written

    // D: h-half dot.
    if (!is_x) {
      float q = 0.f;
      #pragma unroll
      for (int j = 0; j < 16; ++j) {
        const float4 hv = *(const float4*)&hb[(s2 * 64 + j * 4) ^ ((s2 & 3) << 2)];
        q = fmaf(hv.x, wr[j].x, q); q = fmaf(hv.y, wr[j].y, q);
        q = fmaf(hv.z, wr[j].z, q); q = fmaf(hv.w, wr[j].w, q);
      }
      q += __shfl_xor(q, 16);
      q += __shfl_xor(q, 32);
      if (lane < 16) partial[wave][lane] = q;
    }
    __syncthreads();  // all partials ready

    // E: wave 0 reduces, applies gates, publishes tagged h_t.
    if (wave == 0) {
      float zsum = bias_reg;
      #pragma unroll
      for (int wv = 0; wv < 8; ++wv) zsum += partial[wv][lane & 15];
      const float zi = __shfl(zsum, tid);       // lanes 0..3 gather their gates
      const float zj = __shfl(zsum, tid + 4);
      const float zf = __shfl(zsum, tid + 8);
      const float zo = __shfl(zsum, tid + 12);
      if (tid < 4) {
        const float fg = fsig(zf + 1.0f);       // FORGET_BIAS
        const float nc = c_reg * fg + fsig(zi) * ftanh(zj);
        const float nh = ftanh(nc) * fsig(zo);
        c_reg = nc; hlast = nh;
        const u64 pv = ((u64)(unsigned)(t + 1) << 32) | (u64)__float_as_uint(nh);
        __hip_atomic_store(&hbuf[(t & 1) * HH + g * 4 + tid], pv,
                           __ATOMIC_RELAXED, SCOPE_AGENT);
        Hs[(size_t)(t - 1) * HH + g * 4 + tid] = nh;  // fire-and-forget
      }
    }
  }

  if (tid < 4) {
    out_tail[g * 4 + tid]      = c_reg;   // c_last
    out_tail[HH + g * 4 + tid] = hlast;   // h_last
  }
}

// output = hs @ W_out + b_out. fp32 tiled GEMM, 64x64 tile, 4x4/thread.
#define BM 64
#define BN 64
#define BK 16
__global__ __launch_bounds__(256, 2) void out_gemm(
    const float* __restrict__ A,    // hs [8192][1024]
    const float* __restrict__ Bw,   // W_out [1024][1024]
    const float* __restrict__ bias,
    float* __restrict__ C)          // [8192][1024]
{
  __shared__ float As[BM][BK];
  __shared__ float Bs[BK][BN];
  const int tid = threadIdx.x;
  const int row0 = blockIdx.y * BM, col0 = blockIdx.x * BN;
  const int tx = tid & 15, ty = tid >> 4;

  float acc[4][4];
  #pragma unroll
  for (int j = 0; j < 4; ++j) {
    const float bv = bias[col0 + tx * 4 + j];
    #pragma unroll
    for (int i = 0; i < 4; ++i) acc[i][j] = bv;
  }

  for (int k0 = 0; k0 < HH; k0 += BK) {
    {
      const int r = tid >> 2, c = (tid & 3) * 4;
      const float4 va = *(const float4*)&A[(size_t)(row0 + r) * HH + k0 + c];
      As[r][c] = va.x; As[r][c + 1] = va.y; As[r][c + 2] = va.z; As[r][c + 3] = va.w;
      const int rb = tid >> 4, cb = (tid & 15) * 4;
      *(float4*)&Bs[rb][cb] = *(const float4*)&Bw[(size_t)(k0 + rb) * HH + col0 + cb];
    }
    __syncthreads();
    #pragma unroll
    for (int kk = 0; kk < BK; ++kk) {
      float a[4], bv[4];
      #pragma unroll
      for (int i = 0; i < 4; ++i) a[i] = As[ty * 4 + i][kk];
      #pragma unroll
      for (int j = 0; j < 4; ++j) bv[j] = Bs[kk][tx * 4 + j];
      #pragma unroll
      for (int i = 0; i < 4; ++i)
        #pragma unroll
        for (int j = 0; j < 4; ++j)
          acc[i][j] = fmaf(a[i], bv[j], acc[i][j]);
    }
    __syncthreads();
  }

  #pragma unroll
  for (int i = 0; i < 4; ++i) {
    float4 v = make_float4(acc[i][0], acc[i][1], acc[i][2], acc[i][3]);
    *(float4*)&C[(size_t)(row0 + ty * 4 + i) * HH + col0 + tx * 4] = v;
  }
}

extern "C" void kernel_launch(void* const* d_in, const int* in_sizes, int n_in,
                              void* d_out, int out_size, void* d_ws, size_t ws_size,
                              hipStream_t stream) {
  const float* x    = (const float*)d_in[0];
  const float* c_in = (const float*)d_in[1];
  const float* h_in = (const float*)d_in[2];
  const float* W    = (const float*)d_in[3];
  const float* b    = (const float*)d_in[4];
  const float* Wout = (const float*)d_in[5];
  const float* bout = (const float*)d_in[6];
  float* out = (float*)d_out;

  // ws layout: hbuf [2*H u64, 16KB] | Hs [T*H floats, 32MB]
  u64* hbuf = (u64*)d_ws;
  float* Hs = (float*)(hbuf + 2 * HH);
  float* out_tail = out + (size_t)T_STEPS * HH;

  // Tags must start at 0 every launch (graph replays reuse ws).
  hipMemsetAsync(hbuf, 0, 2 * HH * sizeof(u64), stream);

  void* args[] = {(void*)&x, (void*)&c_in, (void*)&h_in, (void*)&W, (void*)&b,
                  (void*)&Hs, (void*)&hbuf, (void*)&out_tail};
  hipLaunchCooperativeKernel((void*)lstm_scan, dim3(NWG), dim3(NTHR),
                             args, 0, stream);

  out_gemm<<<dim3(HH / BN, T_STEPS / BM), 256, 0, stream>>>(Hs, Wout, bout, out);
}

// Round 6
// 16135.774 us; speedup vs baseline: 1.2745x; 1.2745x over previous
//
#include <hip/hip_runtime.h>

#define T_STEPS 8192
#define DD 1024
#define HH 1024
#define NWG 256
#define NTHR 512
#define SCOPE_AGENT __HIP_MEMORY_SCOPE_AGENT
typedef unsigned long long u64;

// XOR swizzle (float index) so the 4 segs of a wave hit distinct bank quads
// when broadcasting 16B chunks to 16 lanes each.
__device__ __forceinline__ int swz(int k) { return k ^ ((((k) >> 6) & 3) << 2); }

__device__ __forceinline__ float fsig(float v) {
  return 1.f / (1.f + __expf(-v));
}
__device__ __forceinline__ float ftanh(float v) {
  return 2.f / (1.f + __expf(-2.f * v)) - 1.f;
}

// Persistent scan: WG g owns h[4g..4g+4). Thread (seg=tid>>4, col=tid&15)
// covers rows k=seg*64..+64 of the 2048-long dot for z-column
// (gate=col>>2)*H + g*4 + (col&3). segs 0..15 = x-part, 16..31 = h-part.
// Weights in packed LDS (conflict-free ds_read_b128) — VGPR-resident weights
// failed twice (allocator spills; round 4/5 post-mortems). h travels as
// 64-bit (tag<<32 | float_bits) atoms, ping-ponged over 2 slots; polls issue
// LATE (phase C) so the first poll usually hits (round-4 lesson). x_t is
// prefetched into registers one step ahead so no global-load stall sits on
// the publish->poll serial chain.
__global__ __launch_bounds__(NTHR, 1) void lstm_scan(
    const float* __restrict__ x, const float* __restrict__ c_in,
    const float* __restrict__ h_in, const float* __restrict__ W,
    const float* __restrict__ b, float* __restrict__ Hs,  // [T][H] = h_1..h_T
    u64* __restrict__ hbuf,         // [2][H] tagged ping-pong (memset 0)
    float* __restrict__ out_tail)   // c_last | h_last
{
  const int g = blockIdx.x, tid = threadIdx.x;
  const int lane = tid & 63, wave = tid >> 6;
  const int col = tid & 15, seg = tid >> 4;
  const int gate = col >> 2, hi = col & 3;
  const int cg = gate * HH + g * 4 + hi;

  __shared__ float Wl[32768];       // 128 KB packed weight slice
  __shared__ float xb[DD];          // swizzled x_t
  __shared__ float hb[HH];          // swizzled h_{t-1}
  __shared__ float partial[8][16];  // per-wave column partials

  float c_reg = 0.f, hlast = 0.f;

  // Publish h_0 immediately (slot 0, tag 1) so consumers' first polls hit.
  if (tid < 4) {
    const float h0 = h_in[g * 4 + tid];
    c_reg = c_in[g * 4 + tid];
    const u64 pv = ((u64)1u << 32) | (u64)__float_as_uint(h0);
    __hip_atomic_store(&hbuf[g * 4 + tid], pv, __ATOMIC_RELAXED, SCOPE_AGENT);
  }

  // One-time weight staging: 64 strided global loads -> packed LDS.
  #pragma unroll
  for (int j = 0; j < 16; ++j) {
    float4 v;
    v.x = W[(size_t)(seg * 64 + j * 4 + 0) * (4 * HH) + cg];
    v.y = W[(size_t)(seg * 64 + j * 4 + 1) * (4 * HH) + cg];
    v.z = W[(size_t)(seg * 64 + j * 4 + 2) * (4 * HH) + cg];
    v.w = W[(size_t)(seg * 64 + j * 4 + 3) * (4 * HH) + cg];
    *(float4*)&Wl[(wave * 16 + j) * 256 + lane * 4] = v;
  }

  // Loop-invariant bias for this thread's column (used by wave 0 only).
  const float bias_reg = b[((lane & 15) >> 2) * HH + g * 4 + (lane & 3)];

  // Prefetch x_1 into registers.
  float xv0 = x[tid], xv1 = x[tid + 512];

  __syncthreads();  // Wl ready

  const bool is_x = (seg < 16);
  const int s2 = seg - 16;

  for (int t = 1; t <= T_STEPS; ++t) {
    // A: stage x_t from prefetch regs (no global stall on the serial chain).
    xb[swz(tid)]       = xv0;
    xb[swz(tid + 512)] = xv1;
    __syncthreads();  // xb ready; prev-step partial reads done

    // B: prefetch x_{t+1} (latency hides under x-dot + poll); x-half dot.
    if (t < T_STEPS) {
      const float* xn = x + (size_t)t * DD;
      xv0 = xn[tid];
      xv1 = xn[tid + 512];
    }
    if (is_x) {
      float p = 0.f;
      #pragma unroll
      for (int j = 0; j < 16; ++j) {
        const float4 wv = *(const float4*)&Wl[(wave * 16 + j) * 256 + lane * 4];
        const float4 xv = *(const float4*)&xb[(seg * 64 + j * 4) ^ ((seg & 3) << 2)];
        p = fmaf(xv.x, wv.x, p); p = fmaf(xv.y, wv.y, p);
        p = fmaf(xv.z, wv.z, p); p = fmaf(xv.w, wv.w, p);
      }
      p += __shfl_xor(p, 16);
      p += __shfl_xor(p, 32);
      if (lane < 16) partial[wave][lane] = p;
    }

    // C: poll tagged h atoms (fresh issue -> first poll usually hits).
    {
      const u64* hp = hbuf + ((t - 1) & 1) * HH;
      u64 v0 = __hip_atomic_load(&hp[tid],       __ATOMIC_RELAXED, SCOPE_AGENT);
      u64 v1 = __hip_atomic_load(&hp[tid + 512], __ATOMIC_RELAXED, SCOPE_AGENT);
      bool r0 = (unsigned)(v0 >> 32) >= (unsigned)t;
      bool r1 = (unsigned)(v1 >> 32) >= (unsigned)t;
      while (!(r0 && r1)) {
        __builtin_amdgcn_s_sleep(1);
        if (!r0) {
          v0 = __hip_atomic_load(&hp[tid], __ATOMIC_RELAXED, SCOPE_AGENT);
          r0 = (unsigned)(v0 >> 32) >= (unsigned)t;
        }
        if (!r1) {
          v1 = __hip_atomic_load(&hp[tid + 512], __ATOMIC_RELAXED, SCOPE_AGENT);
          r1 = (unsigned)(v1 >> 32) >= (unsigned)t;
        }
      }
      hb[swz(tid)]       = __uint_as_float((unsigned)v0);
      hb[swz(tid + 512)] = __uint_as_float((unsigned)v1);
    }
    __syncthreads();  // hb ready + x-partials written

    // D: h-half dot.
    if (!is_x) {
      float q = 0.f;
      #pragma unroll
      for (int j = 0; j < 16; ++j) {
        const float4 wv = *(const float4*)&Wl[(wave * 16 + j) * 256 + lane * 4];
        const float4 hv = *(const float4*)&hb[(s2 * 64 + j * 4) ^ ((s2 & 3) << 2)];
        q = fmaf(hv.x, wv.x, q); q = fmaf(hv.y, wv.y, q);
        q = fmaf(hv.z, wv.z, q); q = fmaf(hv.w, wv.w, q);
      }
      q += __shfl_xor(q, 16);
      q += __shfl_xor(q, 32);
      if (lane < 16) partial[wave][lane] = q;
    }
    __syncthreads();  // all partials ready

    // E: wave 0 reduces, applies gates, publishes tagged h_t.
    if (wave == 0) {
      float zsum = bias_reg;
      #pragma unroll
      for (int wv = 0; wv < 8; ++wv) zsum += partial[wv][lane & 15];
      const float zi = __shfl(zsum, tid);       // lanes 0..3 gather their gates
      const float zj = __shfl(zsum, tid + 4);
      const float zf = __shfl(zsum, tid + 8);
      const float zo = __shfl(zsum, tid + 12);
      if (tid < 4) {
        const float fg = fsig(zf + 1.0f);       // FORGET_BIAS
        const float nc = c_reg * fg + fsig(zi) * ftanh(zj);
        const float nh = ftanh(nc) * fsig(zo);
        c_reg = nc; hlast = nh;
        const u64 pv = ((u64)(unsigned)(t + 1) << 32) | (u64)__float_as_uint(nh);
        __hip_atomic_store(&hbuf[(t & 1) * HH + g * 4 + tid], pv,
                           __ATOMIC_RELAXED, SCOPE_AGENT);
        Hs[(size_t)(t - 1) * HH + g * 4 + tid] = nh;  // fire-and-forget
      }
    }
  }

  if (tid < 4) {
    out_tail[g * 4 + tid]      = c_reg;   // c_last
    out_tail[HH + g * 4 + tid] = hlast;   // h_last
  }
}

// output = hs @ W_out + b_out. fp32 tiled GEMM, 64x64 tile, 4x4/thread.
#define BM 64
#define BN 64
#define BK 16
__global__ __launch_bounds__(256, 2) void out_gemm(
    const float* __restrict__ A,    // hs [8192][1024]
    const float* __restrict__ Bw,   // W_out [1024][1024]
    const float* __restrict__ bias,
    float* __restrict__ C)          // [8192][1024]
{
  __shared__ float As[BM][BK];
  __shared__ float Bs[BK][BN];
  const int tid = threadIdx.x;
  const int row0 = blockIdx.y * BM, col0 = blockIdx.x * BN;
  const int tx = tid & 15, ty = tid >> 4;

  float acc[4][4];
  #pragma unroll
  for (int j = 0; j < 4; ++j) {
    const float bv = bias[col0 + tx * 4 + j];
    #pragma unroll
    for (int i = 0; i < 4; ++i) acc[i][j] = bv;
  }

  for (int k0 = 0; k0 < HH; k0 += BK) {
    {
      const int r = tid >> 2, c = (tid & 3) * 4;
      const float4 va = *(const float4*)&A[(size_t)(row0 + r) * HH + k0 + c];
      As[r][c] = va.x; As[r][c + 1] = va.y; As[r][c + 2] = va.z; As[r][c + 3] = va.w;
      const int rb = tid >> 4, cb = (tid & 15) * 4;
      *(float4*)&Bs[rb][cb] = *(const float4*)&Bw[(size_t)(k0 + rb) * HH + col0 + cb];
    }
    __syncthreads();
    #pragma unroll
    for (int kk = 0; kk < BK; ++kk) {
      float a[4], bv[4];
      #pragma unroll
      for (int i = 0; i < 4; ++i) a[i] = As[ty * 4 + i][kk];
      #pragma unroll
      for (int j = 0; j < 4; ++j) bv[j] = Bs[kk][tx * 4 + j];
      #pragma unroll
      for (int i = 0; i < 4; ++i)
        #pragma unroll
        for (int j = 0; j < 4; ++j)
          acc[i][j] = fmaf(a[i], bv[j], acc[i][j]);
    }
    __syncthreads();
  }

  #pragma unroll
  for (int i = 0; i < 4; ++i) {
    float4 v = make_float4(acc[i][0], acc[i][1], acc[i][2], acc[i][3]);
    *(float4*)&C[(size_t)(row0 + ty * 4 + i) * HH + col0 + tx * 4] = v;
  }
}

extern "C" void kernel_launch(void* const* d_in, const int* in_sizes, int n_in,
                              void* d_out, int out_size, void* d_ws, size_t ws_size,
                              hipStream_t stream) {
  const float* x    = (const float*)d_in[0];
  const float* c_in = (const float*)d_in[1];
  const float* h_in = (const float*)d_in[2];
  const float* W    = (const float*)d_in[3];
  const float* b    = (const float*)d_in[4];
  const float* Wout = (const float*)d_in[5];
  const float* bout = (const float*)d_in[6];
  float* out = (float*)d_out;

  // ws layout: hbuf [2*H u64, 16KB] | Hs [T*H floats, 32MB]
  u64* hbuf = (u64*)d_ws;
  float* Hs = (float*)(hbuf + 2 * HH);
  float* out_tail = out + (size_t)T_STEPS * HH;

  // Tags must start at 0 every launch (graph replays reuse ws).
  hipMemsetAsync(hbuf, 0, 2 * HH * sizeof(u64), stream);

  void* args[] = {(void*)&x, (void*)&c_in, (void*)&h_in, (void*)&W, (void*)&b,
                  (void*)&Hs, (void*)&hbuf, (void*)&out_tail};
  hipLaunchCooperativeKernel((void*)lstm_scan, dim3(NWG), dim3(NTHR),
                             args, 0, stream);

  out_gemm<<<dim3(HH / BN, T_STEPS / BM), 256, 0, stream>>>(Hs, Wout, bout, out);
}

// Round 7
// 12974.921 us; speedup vs baseline: 1.5849x; 1.2436x over previous
//
#include <hip/hip_runtime.h>

#define T_STEPS 8192
#define DD 1024
#define HH 1024
#define NWG 256
#define NTHR 512
#define SCOPE_AGENT __HIP_MEMORY_SCOPE_AGENT
typedef unsigned long long u64;

// XOR swizzle (float index) so the 4 segs of a wave hit distinct bank quads
// when broadcasting 16B chunks to 16 lanes each.
__device__ __forceinline__ int swz(int k) { return k ^ ((((k) >> 6) & 3) << 2); }

__device__ __forceinline__ float fsig(float v) {
  return 1.f / (1.f + __expf(-v));
}
__device__ __forceinline__ float ftanh(float v) {
  return 2.f / (1.f + __expf(-2.f * v)) - 1.f;
}

// Persistent scan, decoupled-chunk schedule. WG g owns h[4g..4g+4).
// Columns: col=tid&15 -> z-column (gate=col>>2)*H + g*4 + (col&3).
// Waves 0-3 ("x-waves"): segs 0-15 of the 2048-dot (x part). Never poll.
// Waves 4-7 ("h-waves"): segs 16-31 (h part). Wave w polls ONLY its own
// 256-element h-chunk [(w-4)*256, +256) (4 tagged atoms/lane), stages it
// into its own hb chunk, and starts its dot with no cross-wave sync
// (same-wave LDS write->read needs only lgkmcnt). Two __syncthreads/step.
// h travels as 64-bit (tag<<32 | float_bits) atoms, 2-slot ping-pong
// (parity argument: producer t-publish implies all consumed t-2 -> safe).
__global__ __launch_bounds__(NTHR, 1) void lstm_scan(
    const float* __restrict__ x, const float* __restrict__ c_in,
    const float* __restrict__ h_in, const float* __restrict__ W,
    const float* __restrict__ b, float* __restrict__ Hs,  // [T][H] = h_1..h_T
    u64* __restrict__ hbuf,         // [2][H] tagged ping-pong (memset 0)
    float* __restrict__ out_tail)   // c_last | h_last
{
  const int g = blockIdx.x, tid = threadIdx.x;
  const int lane = tid & 63, wave = tid >> 6;
  const int col = tid & 15, seg = tid >> 4;
  const int gate = col >> 2, hi = col & 3;
  const int cg = gate * HH + g * 4 + hi;

  __shared__ float Wl[32768];       // 128 KB packed weight slice
  __shared__ float xb[DD];          // swizzled x_t
  __shared__ float hb[HH];          // swizzled h_{t-1} (per-wave chunks)
  __shared__ float partial[8][16];  // per-wave column partials

  float c_reg = 0.f, hlast = 0.f;

  // Publish h_0 immediately (slot 0, tag 1).
  if (tid < 4) {
    const float h0 = h_in[g * 4 + tid];
    c_reg = c_in[g * 4 + tid];
    const u64 pv = ((u64)1u << 32) | (u64)__float_as_uint(h0);
    __hip_atomic_store(&hbuf[g * 4 + tid], pv, __ATOMIC_RELAXED, SCOPE_AGENT);
  }

  // One-time weight staging: 64 strided global loads -> packed LDS.
  // Thread's rows seg*64 + j*4 + 0..3 of column cg (rows >=1024 are Wh).
  #pragma unroll
  for (int j = 0; j < 16; ++j) {
    float4 v;
    v.x = W[(size_t)(seg * 64 + j * 4 + 0) * (4 * HH) + cg];
    v.y = W[(size_t)(seg * 64 + j * 4 + 1) * (4 * HH) + cg];
    v.z = W[(size_t)(seg * 64 + j * 4 + 2) * (4 * HH) + cg];
    v.w = W[(size_t)(seg * 64 + j * 4 + 3) * (4 * HH) + cg];
    *(float4*)&Wl[(wave * 16 + j) * 256 + lane * 4] = v;
  }

  // Loop-invariant bias for this thread's column (used by wave 0 only).
  const float bias_reg = b[((lane & 15) >> 2) * HH + g * 4 + (lane & 3)];

  // Prefetch x_1 into registers.
  float xv0 = x[tid], xv1 = x[tid + 512];

  __syncthreads();  // Wl ready

  const bool is_x = (wave < 4);

  for (int t = 1; t <= T_STEPS; ++t) {
    // A: stage x_t from prefetch regs.
    xb[swz(tid)]       = xv0;
    xb[swz(tid + 512)] = xv1;
    __syncthreads();  // xb ready; partial[] + xb reuse guarded

    // Prefetch x_{t+1} (non-blocking; consumed at next A).
    if (t < T_STEPS) {
      const float* xn = x + (size_t)t * DD;
      xv0 = xn[tid];
      xv1 = xn[tid + 512];
    }

    if (is_x) {
      // x-half dot over segs 0..15.
      float p = 0.f;
      #pragma unroll
      for (int j = 0; j < 16; ++j) {
        const float4 wv = *(const float4*)&Wl[(wave * 16 + j) * 256 + lane * 4];
        const float4 xv = *(const float4*)&xb[(seg * 64 + j * 4) ^ ((seg & 3) << 2)];
        p = fmaf(xv.x, wv.x, p); p = fmaf(xv.y, wv.y, p);
        p = fmaf(xv.z, wv.z, p); p = fmaf(xv.w, wv.w, p);
      }
      p += __shfl_xor(p, 16);
      p += __shfl_xor(p, 32);
      if (lane < 16) partial[wave][lane] = p;
    } else {
      // h-wave: poll own 256-atom chunk (4/lane), no sleep, stale-only retry.
      const u64* hp = hbuf + ((t - 1) & 1) * HH;
      const int cb = (wave - 4) * 256;
      const unsigned tg = (unsigned)t;
      u64 a0 = __hip_atomic_load(&hp[cb + lane],       __ATOMIC_RELAXED, SCOPE_AGENT);
      u64 a1 = __hip_atomic_load(&hp[cb + 64 + lane],  __ATOMIC_RELAXED, SCOPE_AGENT);
      u64 a2 = __hip_atomic_load(&hp[cb + 128 + lane], __ATOMIC_RELAXED, SCOPE_AGENT);
      u64 a3 = __hip_atomic_load(&hp[cb + 192 + lane], __ATOMIC_RELAXED, SCOPE_AGENT);
      bool r0 = (unsigned)(a0 >> 32) >= tg;
      bool r1 = (unsigned)(a1 >> 32) >= tg;
      bool r2 = (unsigned)(a2 >> 32) >= tg;
      bool r3 = (unsigned)(a3 >> 32) >= tg;
      while (!(r0 & r1 & r2 & r3)) {
        if (!r0) { a0 = __hip_atomic_load(&hp[cb + lane],       __ATOMIC_RELAXED, SCOPE_AGENT); r0 = (unsigned)(a0 >> 32) >= tg; }
        if (!r1) { a1 = __hip_atomic_load(&hp[cb + 64 + lane],  __ATOMIC_RELAXED, SCOPE_AGENT); r1 = (unsigned)(a1 >> 32) >= tg; }
        if (!r2) { a2 = __hip_atomic_load(&hp[cb + 128 + lane], __ATOMIC_RELAXED, SCOPE_AGENT); r2 = (unsigned)(a2 >> 32) >= tg; }
        if (!r3) { a3 = __hip_atomic_load(&hp[cb + 192 + lane], __ATOMIC_RELAXED, SCOPE_AGENT); r3 = (unsigned)(a3 >> 32) >= tg; }
      }
      // Stage own chunk (2 lanes/bank after swizzle -> free).
      hb[swz(cb + lane)]       = __uint_as_float((unsigned)a0);
      hb[swz(cb + 64 + lane)]  = __uint_as_float((unsigned)a1);
      hb[swz(cb + 128 + lane)] = __uint_as_float((unsigned)a2);
      hb[swz(cb + 192 + lane)] = __uint_as_float((unsigned)a3);
      // Same-wave LDS write->read: lgkmcnt(0) is sufficient, no barrier.
      asm volatile("s_waitcnt lgkmcnt(0)" ::: "memory");
      // h-half dot over own chunk (segs s2 = (wave-4)*4 + (lane>>4)).
      const int s2 = seg - 16;
      float q = 0.f;
      #pragma unroll
      for (int j = 0; j < 16; ++j) {
        const float4 wv = *(const float4*)&Wl[(wave * 16 + j) * 256 + lane * 4];
        const float4 hv = *(const float4*)&hb[(s2 * 64 + j * 4) ^ ((s2 & 3) << 2)];
        q = fmaf(hv.x, wv.x, q); q = fmaf(hv.y, wv.y, q);
        q = fmaf(hv.z, wv.z, q); q = fmaf(hv.w, wv.w, q);
      }
      q += __shfl_xor(q, 16);
      q += __shfl_xor(q, 32);
      if (lane < 16) partial[wave][lane] = q;
    }
    __syncthreads();  // all 8 partial rows ready

    // E: wave 0 combines, parallel activations on 16 lanes, publishes.
    if (wave == 0) {
      float zsum = bias_reg;
      #pragma unroll
      for (int wv = 0; wv < 8; ++wv) zsum += partial[wv][lane & 15];
      // Uniform activation: gates i,f,o -> sigmoid (f with +1); j -> tanh
      // via tanh(z) = 2*sig(2z) - 1. One __expf, no divergence.
      const int gt = (lane & 15) >> 2;
      const float zin = (gt == 1) ? (2.f * zsum) : (gt == 2 ? zsum + 1.f : zsum);
      const float s = 1.f / (1.f + __expf(-zin));
      const float act = (gt == 1) ? (2.f * s - 1.f) : s;
      const float ig = __shfl(act, tid);        // lanes 0..3 gather their gates
      const float tj = __shfl(act, tid + 4);
      const float fg = __shfl(act, tid + 8);
      const float og = __shfl(act, tid + 12);
      if (tid < 4) {
        const float nc = c_reg * fg + ig * tj;
        const float nh = ftanh(nc) * og;        // single serial transcendental
        c_reg = nc; hlast = nh;
        const u64 pv = ((u64)(unsigned)(t + 1) << 32) | (u64)__float_as_uint(nh);
        __hip_atomic_store(&hbuf[(t & 1) * HH + g * 4 + tid], pv,
                           __ATOMIC_RELAXED, SCOPE_AGENT);
        Hs[(size_t)(t - 1) * HH + g * 4 + tid] = nh;  // fire-and-forget
      }
    }
  }

  if (tid < 4) {
    out_tail[g * 4 + tid]      = c_reg;   // c_last
    out_tail[HH + g * 4 + tid] = hlast;   // h_last
  }
}

// output = hs @ W_out + b_out. fp32 tiled GEMM, 64x64 tile, 4x4/thread.
#define BM 64
#define BN 64
#define BK 16
__global__ __launch_bounds__(256, 2) void out_gemm(
    const float* __restrict__ A,    // hs [8192][1024]
    const float* __restrict__ Bw,   // W_out [1024][1024]
    const float* __restrict__ bias,
    float* __restrict__ C)          // [8192][1024]
{
  __shared__ float As[BM][BK];
  __shared__ float Bs[BK][BN];
  const int tid = threadIdx.x;
  const int row0 = blockIdx.y * BM, col0 = blockIdx.x * BN;
  const int tx = tid & 15, ty = tid >> 4;

  float acc[4][4];
  #pragma unroll
  for (int j = 0; j < 4; ++j) {
    const float bv = bias[col0 + tx * 4 + j];
    #pragma unroll
    for (int i = 0; i < 4; ++i) acc[i][j] = bv;
  }

  for (int k0 = 0; k0 < HH; k0 += BK) {
    {
      const int r = tid >> 2, c = (tid & 3) * 4;
      const float4 va = *(const float4*)&A[(size_t)(row0 + r) * HH + k0 + c];
      As[r][c] = va.x; As[r][c + 1] = va.y; As[r][c + 2] = va.z; As[r][c + 3] = va.w;
      const int rb = tid >> 4, cb = (tid & 15) * 4;
      *(float4*)&Bs[rb][cb] = *(const float4*)&Bw[(size_t)(k0 + rb) * HH + col0 + cb];
    }
    __syncthreads();
    #pragma unroll
    for (int kk = 0; kk < BK; ++kk) {
      float a[4], bv[4];
      #pragma unroll
      for (int i = 0; i < 4; ++i) a[i] = As[ty * 4 + i][kk];
      #pragma unroll
      for (int j = 0; j < 4; ++j) bv[j] = Bs[kk][tx * 4 + j];
      #pragma unroll
      for (int i = 0; i < 4; ++i)
        #pragma unroll
        for (int j = 0; j < 4; ++j)
          acc[i][j] = fmaf(a[i], bv[j], acc[i][j]);
    }
    __syncthreads();
  }

  #pragma unroll
  for (int i = 0; i < 4; ++i) {
    float4 v = make_float4(acc[i][0], acc[i][1], acc[i][2], acc[i][3]);
    *(float4*)&C[(size_t)(row0 + ty * 4 + i) * HH + col0 + tx * 4] = v;
  }
}

extern "C" void kernel_launch(void* const* d_in, const int* in_sizes, int n_in,
                              void* d_out, int out_size, void* d_ws, size_t ws_size,
                              hipStream_t stream) {
  const float* x    = (const float*)d_in[0];
  const float* c_in = (const float*)d_in[1];
  const float* h_in = (const float*)d_in[2];
  const float* W    = (const float*)d_in[3];
  const float* b    = (const float*)d_in[4];
  const float* Wout = (const float*)d_in[5];
  const float* bout = (const float*)d_in[6];
  float* out = (float*)d_out;

  // ws layout: hbuf [2*H u64, 16KB] | Hs [T*H floats, 32MB]
  u64* hbuf = (u64*)d_ws;
  float* Hs = (float*)(hbuf + 2 * HH);
  float* out_tail = out + (size_t)T_STEPS * HH;

  // Tags must start at 0 every launch (graph replays reuse ws).
  hipMemsetAsync(hbuf, 0, 2 * HH * sizeof(u64), stream);

  void* args[] = {(void*)&x, (void*)&c_in, (void*)&h_in, (void*)&W, (void*)&b,
                  (void*)&Hs, (void*)&hbuf, (void*)&out_tail};
  hipLaunchCooperativeKernel((void*)lstm_scan, dim3(NWG), dim3(NTHR),
                             args, 0, stream);

  out_gemm<<<dim3(HH / BN, T_STEPS / BM), 256, 0, stream>>>(Hs, Wout, bout, out);
}